// Round 1
// baseline (422.687 us; speedup 1.0000x reference)
//
#include <hip/hip_runtime.h>
#include <math.h>

// Per point n:
//   s = exp(scaling_raw[n])                       (3,)
//   q = rotation_raw[n] / max(|rotation_raw[n]|, 1e-12)
//   R = quat_to_rotmat(q)                         (3,3)
//   M = R * s[None, :]   (column j scaled by s_j)
//   cov = M @ M^T                                 (3,3) row-major out
//
// N = 8,000,000 = 31250 * 256 exactly -> no tail handling.

constexpr int BLOCK = 256;

__global__ __launch_bounds__(BLOCK) void gaussian_cov_kernel(
    const float* __restrict__ scaling_raw,   // (N,3)
    const float4* __restrict__ rot4,         // (N,4) viewed as float4
    float4* __restrict__ out4,               // (N,9) viewed as float4 (9*N divisible by 4 per-grid; per-block 2304 floats = 576 float4)
    int n)
{
    __shared__ float s_in[BLOCK * 3];    // staged scaling (768 floats)
    __shared__ float s_out[BLOCK * 9];   // staged covariance (2304 floats)

    const int tid  = threadIdx.x;
    const int base = blockIdx.x * BLOCK;

    // ---- stage scaling_raw: 768 floats = 192 float4, coalesced ----
    {
        const float4* sc4 = (const float4*)(scaling_raw + (size_t)base * 3);
        float4* s_in4 = (float4*)s_in;
        if (tid < 192) {
            s_in4[tid] = sc4[tid];
        }
    }

    // ---- rotation: direct float4 load ----
    const float4 qraw = rot4[base + tid];

    __syncthreads();

    // scaling (stride-3 LDS read: gcd(3,32)=1 -> conflict-free)
    const float s0 = expf(s_in[tid * 3 + 0]);
    const float s1 = expf(s_in[tid * 3 + 1]);
    const float s2 = expf(s_in[tid * 3 + 2]);

    // normalize quaternion; clip(norm, 1e-12) == clamp nrm2 at 1e-24
    float w = qraw.x, x = qraw.y, y = qraw.z, z = qraw.w;
    const float nrm2 = w * w + x * x + y * y + z * z;
    const float inv  = rsqrtf(fmaxf(nrm2, 1e-24f));
    w *= inv; x *= inv; y *= inv; z *= inv;

    // rotation matrix
    const float R00 = 1.0f - 2.0f * (y * y + z * z);
    const float R01 = 2.0f * (x * y - w * z);
    const float R02 = 2.0f * (x * z + w * y);
    const float R10 = 2.0f * (x * y + w * z);
    const float R11 = 1.0f - 2.0f * (x * x + z * z);
    const float R12 = 2.0f * (y * z - w * x);
    const float R20 = 2.0f * (x * z - w * y);
    const float R21 = 2.0f * (y * z + w * x);
    const float R22 = 1.0f - 2.0f * (x * x + y * y);

    // M = R * diag(s)  (column j scaled by s_j)
    const float M00 = R00 * s0, M01 = R01 * s1, M02 = R02 * s2;
    const float M10 = R10 * s0, M11 = R11 * s1, M12 = R12 * s2;
    const float M20 = R20 * s0, M21 = R21 * s1, M22 = R22 * s2;

    // cov = M M^T (symmetric)
    const float c00 = M00 * M00 + M01 * M01 + M02 * M02;
    const float c01 = M00 * M10 + M01 * M11 + M02 * M12;
    const float c02 = M00 * M20 + M01 * M21 + M02 * M22;
    const float c11 = M10 * M10 + M11 * M11 + M12 * M12;
    const float c12 = M10 * M20 + M11 * M21 + M12 * M22;
    const float c22 = M20 * M20 + M21 * M21 + M22 * M22;

    // stage into LDS (stride-9 write: gcd(9,32)=1 -> conflict-free)
    float* o = &s_out[tid * 9];
    o[0] = c00; o[1] = c01; o[2] = c02;
    o[3] = c01; o[4] = c11; o[5] = c12;
    o[6] = c02; o[7] = c12; o[8] = c22;

    __syncthreads();

    // drain: 576 float4 coalesced stores
    const float4* s_out4 = (const float4*)s_out;
    float4* dst = out4 + (size_t)blockIdx.x * 576;
    #pragma unroll
    for (int k = 0; k < 576 / BLOCK; ++k) {      // 2 full rounds of 256
        dst[k * BLOCK + tid] = s_out4[k * BLOCK + tid];
    }
    {   // remaining 64
        const int k = 2 * BLOCK + tid;
        if (tid < 576 - 2 * BLOCK) dst[k] = s_out4[k];
    }
}

extern "C" void kernel_launch(void* const* d_in, const int* in_sizes, int n_in,
                              void* d_out, int out_size, void* d_ws, size_t ws_size,
                              hipStream_t stream) {
    const float*  scaling_raw = (const float*)d_in[0];   // (N,3) fp32
    const float4* rot4        = (const float4*)d_in[1];  // (N,4) fp32
    float4*       out4        = (float4*)d_out;          // (N,3,3) fp32

    const int n = in_sizes[0] / 3;                       // 8,000,000
    const int grid = n / BLOCK;                          // 31250, exact

    gaussian_cov_kernel<<<grid, BLOCK, 0, stream>>>(scaling_raw, rot4, out4, n);
}

// Round 3
// 413.081 us; speedup vs baseline: 1.0233x; 1.0233x over previous
//
#include <hip/hip_runtime.h>
#include <math.h>

// Per point n:
//   s = exp(scaling_raw[n]); q = rotation_raw[n]/max(|.|,1e-12)
//   R = quat_to_rotmat(q); M = R*diag(s); cov = M M^T  (3x3 row-major out)
//
// N = 8,000,000 = 15625 blocks * 512 points (2 points/thread, BLOCK=256).

constexpr int BLOCK = 256;
constexpr int PPB   = 512;   // points per block

// clang native vector type: required by __builtin_nontemporal_{load,store}
// (HIP's float4 is a struct and is rejected). Same 16-B layout.
typedef float v4f __attribute__((ext_vector_type(4)));

__device__ __forceinline__ void compute_point(const v4f qraw,
                                              const float* __restrict__ s_scl,
                                              float* __restrict__ o)
{
    const float s0 = __expf(s_scl[0]);
    const float s1 = __expf(s_scl[1]);
    const float s2 = __expf(s_scl[2]);

    float w = qraw.x, x = qraw.y, y = qraw.z, z = qraw.w;
    const float nrm2 = w * w + x * x + y * y + z * z;
    const float inv  = rsqrtf(fmaxf(nrm2, 1e-24f));
    w *= inv; x *= inv; y *= inv; z *= inv;

    const float R00 = 1.0f - 2.0f * (y * y + z * z);
    const float R01 = 2.0f * (x * y - w * z);
    const float R02 = 2.0f * (x * z + w * y);
    const float R10 = 2.0f * (x * y + w * z);
    const float R11 = 1.0f - 2.0f * (x * x + z * z);
    const float R12 = 2.0f * (y * z - w * x);
    const float R20 = 2.0f * (x * z - w * y);
    const float R21 = 2.0f * (y * z + w * x);
    const float R22 = 1.0f - 2.0f * (x * x + y * y);

    const float M00 = R00 * s0, M01 = R01 * s1, M02 = R02 * s2;
    const float M10 = R10 * s0, M11 = R11 * s1, M12 = R12 * s2;
    const float M20 = R20 * s0, M21 = R21 * s1, M22 = R22 * s2;

    const float c00 = M00 * M00 + M01 * M01 + M02 * M02;
    const float c01 = M00 * M10 + M01 * M11 + M02 * M12;
    const float c02 = M00 * M20 + M01 * M21 + M02 * M22;
    const float c11 = M10 * M10 + M11 * M11 + M12 * M12;
    const float c12 = M10 * M20 + M11 * M21 + M12 * M22;
    const float c22 = M20 * M20 + M21 * M21 + M22 * M22;

    o[0] = c00; o[1] = c01; o[2] = c02;
    o[3] = c01; o[4] = c11; o[5] = c12;
    o[6] = c02; o[7] = c12; o[8] = c22;
}

__global__ __launch_bounds__(BLOCK) void gaussian_cov_kernel(
    const v4f* __restrict__ sc4_g,   // scaling_raw viewed as v4f stream
    const v4f* __restrict__ rot4,    // (N,4) as v4f
    v4f* __restrict__ out4)          // (N,9) as v4f
{
    __shared__ float s_in[PPB * 3];     // 6 KB
    __shared__ float s_out[PPB * 9];    // 18 KB

    const int tid   = threadIdx.x;
    const long base = (long)blockIdx.x * PPB;

    // ---- stage scaling: PPB*3 = 1536 floats = 384 v4f, coalesced, nt ----
    {
        const v4f* src = sc4_g + (long)blockIdx.x * (PPB * 3 / 4);  // *384
        v4f* dst = (v4f*)s_in;
        dst[tid] = __builtin_nontemporal_load(&src[tid]);
        if (tid < 128)
            dst[BLOCK + tid] = __builtin_nontemporal_load(&src[BLOCK + tid]);
    }

    // ---- rotation: one v4f per point, 2 points/thread, nt ----
    const v4f q0 = __builtin_nontemporal_load(&rot4[base + tid]);
    const v4f q1 = __builtin_nontemporal_load(&rot4[base + BLOCK + tid]);

    __syncthreads();

    // stride-3 LDS reads / stride-9 LDS writes: gcd(.,32)=1 -> <=2-way, free
    compute_point(q0, &s_in[tid * 3],           &s_out[tid * 9]);
    compute_point(q1, &s_in[(BLOCK + tid) * 3], &s_out[(BLOCK + tid) * 9]);

    __syncthreads();

    // ---- drain: PPB*9 = 4608 floats = 1152 v4f, coalesced, nt ----
    const v4f* srcv = (const v4f*)s_out;
    v4f* dstv = out4 + (long)blockIdx.x * (PPB * 9 / 4);            // *1152
    #pragma unroll
    for (int k = 0; k < 4; ++k)
        __builtin_nontemporal_store(srcv[k * BLOCK + tid], &dstv[k * BLOCK + tid]);
    if (tid < 128)
        __builtin_nontemporal_store(srcv[4 * BLOCK + tid], &dstv[4 * BLOCK + tid]);
}

extern "C" void kernel_launch(void* const* d_in, const int* in_sizes, int n_in,
                              void* d_out, int out_size, void* d_ws, size_t ws_size,
                              hipStream_t stream) {
    const v4f* sc4  = (const v4f*)d_in[0];  // (N,3) fp32
    const v4f* rot4 = (const v4f*)d_in[1];  // (N,4) fp32
    v4f*       out4 = (v4f*)d_out;          // (N,3,3) fp32

    const int n    = in_sizes[0] / 3;       // 8,000,000
    const int grid = n / PPB;               // 15625, exact

    gaussian_cov_kernel<<<grid, BLOCK, 0, stream>>>(sc4, rot4, out4);
}